// Round 1
// baseline (68.018 us; speedup 1.0000x reference)
//
#include <hip/hip_runtime.h>

// FullTensorProduct: irreps_in1 = 64x0e + 64x1o (256 f32/row)
//                    irreps_in2 = 1x0e + 1x1o   (4 f32/row)
// Output (after INV reorder), per row, 1024 f32:
//   [0,64)     path0: 0e*0e -> 0e      s1[u]*s2
//   [64,128)   path3: 1o.1o -> 0e      dot(a,b)/sqrt(3)
//   [128,320)  path1: 0e*1o -> 1o      s1[u]*b[k]
//   [320,512)  path2: 1o*0e -> 1o      a[u,k]*s2
//   [512,704)  path4: 1oX1o -> 1e      cross(a,b)[k]/sqrt(2)
//   [704,1024) path5: 1o 1o -> 2e      sym traceless, 5 comps
// e3nn real l=1 index order is (y,z,x): a0=y a1=z a2=x.

__global__ __launch_bounds__(256) void ftp_kernel(
    const float* __restrict__ in1,
    const float* __restrict__ in2,
    float* __restrict__ out,
    int N)
{
    int t = blockIdx.x * blockDim.x + threadIdx.x;
    int n = t >> 6;       // row index (wave per row)
    int u = t & 63;       // multiplicity index
    if (n >= N) return;

    const float* __restrict__ r1 = in1 + (size_t)n * 256;
    const float* __restrict__ r2 = in2 + (size_t)n * 4;

    // wave-uniform broadcast loads (same addr across all 64 lanes)
    float s2 = r2[0];
    float b0 = r2[1], b1 = r2[2], b2 = r2[3];

    // per-lane loads: s1 coalesced, a = 3 contiguous floats/lane
    float s1 = r1[u];
    int vb = 64 + 3 * u;
    float a0 = r1[vb + 0];
    float a1 = r1[vb + 1];
    float a2 = r1[vb + 2];

    float* __restrict__ o = out + (size_t)n * 1024;

    const float inv_sqrt3 = 0.5773502691896258f;
    const float inv_sqrt2 = 0.7071067811865476f;
    const float inv_sqrt6 = 0.4082482904638630f;

    // path0: 0e x 0e -> 0e
    o[u] = s1 * s2;

    // path3: 1o . 1o -> 0e
    o[64 + u] = (a0 * b0 + a1 * b1 + a2 * b2) * inv_sqrt3;

    // path1: 0e x 1o -> 1o
    int p1 = 128 + 3 * u;
    o[p1 + 0] = s1 * b0;
    o[p1 + 1] = s1 * b1;
    o[p1 + 2] = s1 * b2;

    // path2: 1o x 0e -> 1o
    int p2 = 320 + 3 * u;
    o[p2 + 0] = a0 * s2;
    o[p2 + 1] = a1 * s2;
    o[p2 + 2] = a2 * s2;

    // path4: 1o x 1o -> 1e  (cross product / sqrt2, eps_{012}=+1)
    int p4 = 512 + 3 * u;
    o[p4 + 0] = (a1 * b2 - a2 * b1) * inv_sqrt2;
    o[p4 + 1] = (a2 * b0 - a0 * b2) * inv_sqrt2;
    o[p4 + 2] = (a0 * b1 - a1 * b0) * inv_sqrt2;

    // path5: 1o x 1o -> 2e  (real order: xy, yz, z^2, zx, x^2-y^2; y=0,z=1,x=2)
    int p5 = 704 + 5 * u;
    o[p5 + 0] = (a2 * b0 + a0 * b2) * inv_sqrt2;
    o[p5 + 1] = (a0 * b1 + a1 * b0) * inv_sqrt2;
    o[p5 + 2] = (2.0f * a1 * b1 - a2 * b2 - a0 * b0) * inv_sqrt6;
    o[p5 + 3] = (a1 * b2 + a2 * b1) * inv_sqrt2;
    o[p5 + 4] = (a2 * b2 - a0 * b0) * inv_sqrt2;
}

extern "C" void kernel_launch(void* const* d_in, const int* in_sizes, int n_in,
                              void* d_out, int out_size, void* d_ws, size_t ws_size,
                              hipStream_t stream)
{
    const float* in1 = (const float*)d_in[0];
    const float* in2 = (const float*)d_in[1];
    float* out = (float*)d_out;
    int N = in_sizes[0] / 256;   // 65536

    int total_threads = N * 64;
    int block = 256;
    int grid = (total_threads + block - 1) / block;
    ftp_kernel<<<grid, block, 0, stream>>>(in1, in2, out, N);
}

// Round 2
// 64.107 us; speedup vs baseline: 1.0610x; 1.0610x over previous
//
#include <hip/hip_runtime.h>

// FullTensorProduct: irreps_in1 = 64x0e + 64x1o (256 f32/row)
//                    irreps_in2 = 1x0e + 1x1o   (4 f32/row)
// Output (after INV reorder), per row, 1024 f32:
//   [0,64)     path0: 0e*0e -> 0e      s1[u]*s2
//   [64,128)   path3: 1o.1o -> 0e      dot(a,b)/sqrt(3)
//   [128,320)  path1: 0e*1o -> 1o      s1[u]*b[k]
//   [320,512)  path2: 1o*0e -> 1o      a[u,k]*s2
//   [512,704)  path4: 1oX1o -> 1e      cross(a,b)[k]/sqrt(2)
//   [704,1024) path5: 1o 1o -> 2e      sym traceless, 5 comps
// e3nn real l=1 index order is (y,z,x): a0=y a1=z a2=x.
//
// R1: outputs staged in LDS (scattered writes are <=2-way bank aliasing:
// per-lane word strides 1/3/5 -> exactly 2 lanes/bank = free), then flushed
// as fully-coalesced float4 stores (64 lanes x 16B = 1KB/instr). 16KB LDS
// per 256-thread block -> 8 blocks/CU = full 32-wave occupancy.

__global__ __launch_bounds__(256) void ftp_kernel(
    const float* __restrict__ in1,
    const float* __restrict__ in2,
    float* __restrict__ out,
    int N)
{
    __shared__ float s_out[4][1024];

    int w = threadIdx.x >> 6;   // wave within block (row within block)
    int u = threadIdx.x & 63;   // multiplicity index
    int n = (blockIdx.x << 2) + w;

    if (n < N) {
        const float* __restrict__ r1 = in1 + (size_t)n * 256;
        const float* __restrict__ r2 = in2 + (size_t)n * 4;

        // wave-uniform broadcast loads
        float s2 = r2[0];
        float b0 = r2[1], b1 = r2[2], b2 = r2[3];

        // per-lane loads: s1 coalesced, a = 3 contiguous floats/lane
        float s1 = r1[u];
        int vb = 64 + 3 * u;
        float a0 = r1[vb + 0];
        float a1 = r1[vb + 1];
        float a2 = r1[vb + 2];

        float* __restrict__ so = s_out[w];

        const float inv_sqrt3 = 0.5773502691896258f;
        const float inv_sqrt2 = 0.7071067811865476f;
        const float inv_sqrt6 = 0.4082482904638630f;

        // path0: 0e x 0e -> 0e
        so[u] = s1 * s2;

        // path3: 1o . 1o -> 0e
        so[64 + u] = (a0 * b0 + a1 * b1 + a2 * b2) * inv_sqrt3;

        // path1: 0e x 1o -> 1o
        int p1 = 128 + 3 * u;
        so[p1 + 0] = s1 * b0;
        so[p1 + 1] = s1 * b1;
        so[p1 + 2] = s1 * b2;

        // path2: 1o x 0e -> 1o
        int p2 = 320 + 3 * u;
        so[p2 + 0] = a0 * s2;
        so[p2 + 1] = a1 * s2;
        so[p2 + 2] = a2 * s2;

        // path4: 1o x 1o -> 1e  (cross / sqrt2, eps_{012}=+1)
        int p4 = 512 + 3 * u;
        so[p4 + 0] = (a1 * b2 - a2 * b1) * inv_sqrt2;
        so[p4 + 1] = (a2 * b0 - a0 * b2) * inv_sqrt2;
        so[p4 + 2] = (a0 * b1 - a1 * b0) * inv_sqrt2;

        // path5: 1o x 1o -> 2e  (xy, yz, z^2, zx, x^2-y^2; y=0,z=1,x=2)
        int p5 = 704 + 5 * u;
        so[p5 + 0] = (a2 * b0 + a0 * b2) * inv_sqrt2;
        so[p5 + 1] = (a0 * b1 + a1 * b0) * inv_sqrt2;
        so[p5 + 2] = (2.0f * a1 * b1 - a2 * b2 - a0 * b0) * inv_sqrt6;
        so[p5 + 3] = (a1 * b2 + a2 * b1) * inv_sqrt2;
        so[p5 + 4] = (a2 * b2 - a0 * b0) * inv_sqrt2;
    }

    __syncthreads();

    // Cooperative flush: block's 4 rows are 4096 contiguous floats in global.
    // s_out[4][1024] flat == the same 4096 floats. 4 x float4 per thread.
    size_t base = (size_t)blockIdx.x * 4096;
    if (base + 4096 <= (size_t)N * 1024) {
        const float4* __restrict__ sf = (const float4*)&s_out[0][0];
        float4* __restrict__ of = (float4*)(out + base);
        #pragma unroll
        for (int c = 0; c < 4; ++c) {
            int i = threadIdx.x + 256 * c;
            of[i] = sf[i];
        }
    } else {
        // tail block (not hit for N=65536): scalar-safe flush
        const float* __restrict__ sf = &s_out[0][0];
        for (int c = 0; c < 4; ++c) {
            int i = threadIdx.x + 256 * c;
            size_t idx = base + (size_t)i * 4;
            for (int k = 0; k < 4; ++k) {
                size_t g = idx + k;
                if (g < (size_t)N * 1024) out[g] = sf[i * 4 + k];
            }
        }
    }
}

extern "C" void kernel_launch(void* const* d_in, const int* in_sizes, int n_in,
                              void* d_out, int out_size, void* d_ws, size_t ws_size,
                              hipStream_t stream)
{
    const float* in1 = (const float*)d_in[0];
    const float* in2 = (const float*)d_in[1];
    float* out = (float*)d_out;
    int N = in_sizes[0] / 256;   // 65536

    int rows_per_block = 4;
    int grid = (N + rows_per_block - 1) / rows_per_block;
    ftp_kernel<<<grid, 256, 0, stream>>>(in1, in2, out, N);
}

// Round 4
// 63.203 us; speedup vs baseline: 1.0762x; 1.0143x over previous
//
#include <hip/hip_runtime.h>

// FullTensorProduct: irreps_in1 = 64x0e + 64x1o (256 f32/row)
//                    irreps_in2 = 1x0e + 1x1o   (4 f32/row)
// Output (after INV reorder), per row, 1024 f32:
//   [0,64)     path0: 0e*0e -> 0e      s1[u]*s2
//   [64,128)   path3: 1o.1o -> 0e      dot(a,b)/sqrt(3)
//   [128,320)  path1: 0e*1o -> 1o      s1[u]*b[k]
//   [320,512)  path2: 1o*0e -> 1o      a[u,k]*s2
//   [512,704)  path4: 1oX1o -> 1e      cross(a,b)[k]/sqrt(2)
//   [704,1024) path5: 1o 1o -> 2e      sym traceless, 5 comps
// e3nn real l=1 index order is (y,z,x): a0=y a1=z a2=x.
//
// R1: LDS-staged outputs -> fully coalesced float4 stores. 68 -> 64.1 us.
// R2/R3: in1 staged via cooperative 16B loads (all global loads dwordx4),
//     operands read from LDS (stride 1/3 = <=2-way bank aliasing = free);
//     nontemporal hints via clang ext_vector_type (HIP float4 is a class
//     and rejected by __builtin_nontemporal_*).

typedef float f32x4 __attribute__((ext_vector_type(4)));

__global__ __launch_bounds__(256) void ftp_kernel(
    const float* __restrict__ in1,
    const float* __restrict__ in2,
    float* __restrict__ out,
    int N)
{
    __shared__ float s_in[4 * 256];     // block's 4 in1 rows
    __shared__ float s_out[4][1024];    // block's 4 output rows

    int w = threadIdx.x >> 6;   // wave within block (row within block)
    int u = threadIdx.x & 63;   // multiplicity index
    int n = (blockIdx.x << 2) + w;

    // ---- cooperative in1 stage: 4 rows x 256 floats = 256 float4, 1/thread
    size_t ibase = (size_t)blockIdx.x * 1024;            // floats
    if (ibase + 1024 <= (size_t)N * 256) {
        const f32x4* __restrict__ g4 = (const f32x4*)(in1 + ibase);
        ((f32x4*)s_in)[threadIdx.x] =
            __builtin_nontemporal_load(&g4[threadIdx.x]);
    } else {
        for (int k = threadIdx.x; k < 1024; k += 256) {
            size_t g = ibase + k;
            s_in[k] = (g < (size_t)N * 256) ? in1[g] : 0.0f;
        }
    }
    __syncthreads();

    if (n < N) {
        const float* __restrict__ r2 = in2 + (size_t)n * 4;

        // wave-uniform broadcast loads (16B/row total; L1/L2-served)
        float s2 = r2[0];
        float b0 = r2[1], b1 = r2[2], b2 = r2[3];

        // operands from LDS: stride-1 and stride-3 scalar reads (conflict-free)
        const float* __restrict__ r1 = &s_in[w * 256];
        float s1 = r1[u];
        int vb = 64 + 3 * u;
        float a0 = r1[vb + 0];
        float a1 = r1[vb + 1];
        float a2 = r1[vb + 2];

        float* __restrict__ so = s_out[w];

        const float inv_sqrt3 = 0.5773502691896258f;
        const float inv_sqrt2 = 0.7071067811865476f;
        const float inv_sqrt6 = 0.4082482904638630f;

        // path0: 0e x 0e -> 0e
        so[u] = s1 * s2;

        // path3: 1o . 1o -> 0e
        so[64 + u] = (a0 * b0 + a1 * b1 + a2 * b2) * inv_sqrt3;

        // path1: 0e x 1o -> 1o
        int p1 = 128 + 3 * u;
        so[p1 + 0] = s1 * b0;
        so[p1 + 1] = s1 * b1;
        so[p1 + 2] = s1 * b2;

        // path2: 1o x 0e -> 1o
        int p2 = 320 + 3 * u;
        so[p2 + 0] = a0 * s2;
        so[p2 + 1] = a1 * s2;
        so[p2 + 2] = a2 * s2;

        // path4: 1o x 1o -> 1e  (cross / sqrt2, eps_{012}=+1)
        int p4 = 512 + 3 * u;
        so[p4 + 0] = (a1 * b2 - a2 * b1) * inv_sqrt2;
        so[p4 + 1] = (a2 * b0 - a0 * b2) * inv_sqrt2;
        so[p4 + 2] = (a0 * b1 - a1 * b0) * inv_sqrt2;

        // path5: 1o x 1o -> 2e  (xy, yz, z^2, zx, x^2-y^2; y=0,z=1,x=2)
        int p5 = 704 + 5 * u;
        so[p5 + 0] = (a2 * b0 + a0 * b2) * inv_sqrt2;
        so[p5 + 1] = (a0 * b1 + a1 * b0) * inv_sqrt2;
        so[p5 + 2] = (2.0f * a1 * b1 - a2 * b2 - a0 * b0) * inv_sqrt6;
        so[p5 + 3] = (a1 * b2 + a2 * b1) * inv_sqrt2;
        so[p5 + 4] = (a2 * b2 - a0 * b0) * inv_sqrt2;
    }

    __syncthreads();

    // Cooperative flush: block's 4 rows are 4096 contiguous floats in global.
    size_t base = (size_t)blockIdx.x * 4096;
    if (base + 4096 <= (size_t)N * 1024) {
        const f32x4* __restrict__ sf = (const f32x4*)&s_out[0][0];
        f32x4* __restrict__ of = (f32x4*)(out + base);
        #pragma unroll
        for (int c = 0; c < 4; ++c) {
            int i = threadIdx.x + 256 * c;
            __builtin_nontemporal_store(sf[i], &of[i]);
        }
    } else {
        // tail block (not hit for N=65536): scalar-safe flush
        const float* __restrict__ sf = &s_out[0][0];
        for (int c = 0; c < 4; ++c) {
            int i = threadIdx.x + 256 * c;
            size_t idx = base + (size_t)i * 4;
            for (int k = 0; k < 4; ++k) {
                size_t g = idx + k;
                if (g < (size_t)N * 1024) out[g] = sf[i * 4 + k];
            }
        }
    }
}

extern "C" void kernel_launch(void* const* d_in, const int* in_sizes, int n_in,
                              void* d_out, int out_size, void* d_ws, size_t ws_size,
                              hipStream_t stream)
{
    const float* in1 = (const float*)d_in[0];
    const float* in2 = (const float*)d_in[1];
    float* out = (float*)d_out;
    int N = in_sizes[0] / 256;   // 65536

    int rows_per_block = 4;
    int grid = (N + rows_per_block - 1) / rows_per_block;
    ftp_kernel<<<grid, 256, 0, stream>>>(in1, in2, out, N);
}